// Round 12
// baseline (655.560 us; speedup 1.0000x reference)
//
#include <hip/hip_runtime.h>

// Paged attention decode, GQA: B=32, H=32, KVH=8 (G=4), D=128, pages of 16.
// R12 = R7 (best: 149.7us) + DIAGNOSTIC linear read-only probe to measure the
// machine's pure-read HBM ceiling (every prior denominator was a copy/write
// figure). Probe: grid-stride float4 sweep of the full 512MB v_cache, 6 reps,
// so it surfaces in the rocprof top-5. Readout decides roofline vs continue.

constexpr int Dh   = 128;
constexpr int Gq   = 4;
constexpr int KVH  = 8;
constexpr int Hq   = 32;
constexpr int Bb   = 32;
constexpr int MB   = 256;
constexpr int PAGE = 16;
constexpr float SCALE = 0.08838834764831845f;

constexpr int NPARTS      = 64;
constexpr int PART_TOKENS = 64;                  // 4 pages per part
constexpr int PG_FLOATS   = PAGE * KVH * Dh;     // 16384 floats = 64 KB
constexpr int ROW_FLOATS  = KVH * Dh;            // 1024 floats per token row

// per-(b,part) workspace floats: acc[32 heads][128] + m[32] + l[32]
constexpr int PART_STRIDE = Hq * Dh + 2 * Hq;    // 4160

struct QuadR { float4 k[4], v[4]; };             // 4 tokens x 4 dims of K and V

__global__ __launch_bounds__(256, 3)
void attn_partial(const float* __restrict__ q,
                  const float* __restrict__ kc,
                  const float* __restrict__ vc,
                  const int*   __restrict__ bt,
                  const int*   __restrict__ cl,
                  float*       __restrict__ ws)
{
    const int part = blockIdx.x & (NPARTS - 1);
    const int b    = blockIdx.x >> 6;

    const int ctx    = cl[b];
    const int pstart = part * PART_TOKENS;
    if (pstart >= ctx) return;
    const int n  = min(PART_TOKENS, ctx - pstart);
    const int TC = (n + 3) >> 2;                 // 4-token chunks, 1..16

    const int t      = threadIdx.x;              // 0..255
    const int kvh    = t >> 5;
    const int lane32 = t & 31;
    const int doff   = lane32 * 4;
    const int t4     = t * 4;

    const int4 pg = *(const int4*)(bt + b * MB + (pstart >> 4));

    float4 qv[Gq];
    {
        const float* qbase = q + (size_t)(b * Hq + kvh * Gq) * Dh + doff;
        #pragma unroll
        for (int g = 0; g < Gq; ++g) {
            float4 x = *(const float4*)(qbase + g * Dh);
            qv[g] = make_float4(x.x * SCALE, x.y * SCALE, x.z * SCALE, x.w * SCALE);
        }
    }

    float4 acc[Gq];
    float  m_run[Gq], l_run[Gq];
    #pragma unroll
    for (int g = 0; g < Gq; ++g) {
        acc[g] = make_float4(0.f, 0.f, 0.f, 0.f);
        m_run[g] = -1e30f;
        l_run[g] = 0.f;
    }

    auto physof = [&](int c) -> int {
        const int p = c >> 2;
        return p == 0 ? pg.x : (p == 1 ? pg.y : (p == 2 ? pg.z : pg.w));
    };

    auto LOADQ = [&](QuadR& H, int c) {
        const size_t off = (size_t)physof(c) * PG_FLOATS
                         + (size_t)((c & 3) * 4) * ROW_FLOATS + t4;
        const float* kp = kc + off;
        const float* vp = vc + off;
        #pragma unroll
        for (int j = 0; j < 4; ++j) {
            H.k[j] = *(const float4*)(kp + j * ROW_FLOATS);
            H.v[j] = *(const float4*)(vp + j * ROW_FLOATS);
        }
    };

    auto COMPUTEQ = [&](const QuadR& H, int c) {
        const int tb = c * 4;
        float s[4][Gq];
        #pragma unroll
        for (int j = 0; j < 4; ++j) {
            const bool vj = (tb + j) < n;
            #pragma unroll
            for (int g = 0; g < Gq; ++g) {
                float d = H.k[j].x * qv[g].x + H.k[j].y * qv[g].y
                        + H.k[j].z * qv[g].z + H.k[j].w * qv[g].w;
                d += __shfl_xor(d, 1);
                d += __shfl_xor(d, 2);
                d += __shfl_xor(d, 4);
                d += __shfl_xor(d, 8);
                d += __shfl_xor(d, 16);          // full dot in all 32 lanes
                s[j][g] = vj ? d : -1e30f;
            }
        }
        #pragma unroll
        for (int g = 0; g < Gq; ++g) {
            const float tm = fmaxf(fmaxf(s[0][g], s[1][g]), fmaxf(s[2][g], s[3][g]));
            const float mn    = fmaxf(m_run[g], tm);
            const float alpha = __expf(m_run[g] - mn);
            m_run[g] = mn;
            const float p0 = __expf(s[0][g] - mn);
            const float p1 = __expf(s[1][g] - mn);
            const float p2 = __expf(s[2][g] - mn);
            const float p3 = __expf(s[3][g] - mn);
            l_run[g] = l_run[g] * alpha + (p0 + p1 + p2 + p3);
            acc[g].x = fmaf(p3, H.v[3].x, fmaf(p2, H.v[2].x,
                       fmaf(p1, H.v[1].x, fmaf(p0, H.v[0].x, acc[g].x * alpha))));
            acc[g].y = fmaf(p3, H.v[3].y, fmaf(p2, H.v[2].y,
                       fmaf(p1, H.v[1].y, fmaf(p0, H.v[0].y, acc[g].y * alpha))));
            acc[g].z = fmaf(p3, H.v[3].z, fmaf(p2, H.v[2].z,
                       fmaf(p1, H.v[1].z, fmaf(p0, H.v[0].z, acc[g].z * alpha))));
            acc[g].w = fmaf(p3, H.v[3].w, fmaf(p2, H.v[2].w,
                       fmaf(p1, H.v[1].w, fmaf(p0, H.v[0].w, acc[g].w * alpha))));
        }
    };

    QuadR A, B;
    LOADQ(A, 0);
    int c = 0;
    while (true) {
        if (c + 1 < TC) LOADQ(B, c + 1);
        COMPUTEQ(A, c);
        ++c; if (c >= TC) break;
        if (c + 1 < TC) LOADQ(A, c + 1);
        COMPUTEQ(B, c);
        ++c; if (c >= TC) break;
    }

    float* wp = ws + (size_t)(b * NPARTS + part) * PART_STRIDE;
    #pragma unroll
    for (int g = 0; g < Gq; ++g)
        *(float4*)(wp + (kvh * Gq + g) * Dh + doff) = acc[g];
    if (lane32 == 0) {
        #pragma unroll
        for (int g = 0; g < Gq; ++g) {
            wp[Hq * Dh + kvh * Gq + g]      = m_run[g];
            wp[Hq * Dh + Hq + kvh * Gq + g] = l_run[g];
        }
    }
}

__global__ __launch_bounds__(256, 4)
void attn_reduce(const float* __restrict__ ws,
                 const int*   __restrict__ cl,
                 float*       __restrict__ out)
{
    const int b       = blockIdx.x >> 2;
    const int quarter = blockIdx.x & 3;
    const int tid     = threadIdx.x;
    const int h       = quarter * 8 + (tid >> 5);
    const int doff    = (tid & 31) * 4;

    const int ctx = cl[b];
    const int np  = min(NPARTS, (ctx + PART_TOKENS - 1) / PART_TOKENS);

    const float* base = ws + (size_t)b * NPARTS * PART_STRIDE;

    float m = -1e30f;
    for (int p = 0; p < np; ++p)
        m = fmaxf(m, base[p * PART_STRIDE + Hq * Dh + h]);

    float L = 0.f;
    float ax = 0.f, ay = 0.f, az = 0.f, aw = 0.f;
    for (int p = 0; p < np; ++p) {
        const float* bp = base + p * PART_STRIDE;
        const float c = __expf(bp[Hq * Dh + h] - m);
        L += bp[Hq * Dh + Hq + h] * c;
        const float4 v = *(const float4*)(bp + h * Dh + doff);
        ax = fmaf(c, v.x, ax);
        ay = fmaf(c, v.y, ay);
        az = fmaf(c, v.z, az);
        aw = fmaf(c, v.w, aw);
    }
    const float inv = 1.f / L;
    float* op = out + (size_t)(b * Hq + h) * Dh + doff;
    *(float4*)op = make_float4(ax * inv, ay * inv, az * inv, aw * inv);
}

// DIAGNOSTIC: pure linear read-only stream over the full 512MB v_cache,
// 6 reps, full occupancy, trivial VALU. Measures the machine's sustainable
// read-only HBM rate -- the denominator for the roofline decision.
__global__ __launch_bounds__(256, 8)
void linear_probe(const float* __restrict__ vc, float* __restrict__ sink)
{
    const size_t nf4    = (size_t)Bb * MB * PG_FLOATS / 4;   // 33.5M float4
    const size_t stride = (size_t)gridDim.x * 256;
    const size_t tid0   = (size_t)blockIdx.x * 256 + threadIdx.x;
    const float4* v4 = (const float4*)vc;
    float acc = 0.f;
    for (int rep = 0; rep < 6; ++rep) {
        for (size_t i = tid0; i < nf4; i += stride) {
            const float4 a = v4[i];
            acc += a.x + a.y + a.z + a.w;
        }
    }
    sink[tid0] = acc;
}

extern "C" void kernel_launch(void* const* d_in, const int* in_sizes, int n_in,
                              void* d_out, int out_size, void* d_ws, size_t ws_size,
                              hipStream_t stream) {
    const float* q  = (const float*)d_in[0];
    const float* kc = (const float*)d_in[1];
    const float* vc = (const float*)d_in[2];
    const int*   bt = (const int*)d_in[3];
    const int*   cl = (const int*)d_in[4];
    float* out = (float*)d_out;
    float* ws  = (float*)d_ws;

    attn_partial<<<dim3(Bb * NPARTS), dim3(256), 0, stream>>>(q, kc, vc, bt, cl, ws);
    attn_reduce<<<dim3(Bb * 4), dim3(256), 0, stream>>>(ws, cl, out);

    // diagnostic probe (remove once the read ceiling is established)
    float* sink = ws + ((size_t)1 << 25);        // 128 MB offset, clear of partials
    linear_probe<<<dim3(2048), dim3(256), 0, stream>>>(vc, sink);
}

// Round 13
// 149.373 us; speedup vs baseline: 4.3887x; 4.3887x over previous
//
#include <hip/hip_runtime.h>

// Paged attention decode, GQA: B=32, H=32, KVH=8 (G=4), D=128, pages of 16.
// FINAL (= R7, best measured: 149.7us; R12's diagnostic probe removed).
//  - Flash-decoding split-K: block = (b, part=64 tokens); 256 threads span the
//    full 4KB token row (t -> kvh = t>>5, dims (t&31)*4) so each physical page
//    is read exactly once, contiguously, by one block.
//  - 4-token chunks with rolled even/odd register double-buffer: next chunk's
//    8 float4 loads are in flight during current chunk's compute.
//  - No LDS, no barriers; scores via 5-step shfl_xor butterfly within 32-lane
//    kvh groups; online softmax in-register; PV in-lane FMA.
//  - __launch_bounds__(256,3): 12 waves/CU.
//  - Roofline evidence (R5/R6/R12 probes + 8 structural variants): pure-read
//    HBM service caps ~3.8-4.0 TB/s on this machine for read-once streams
//    (L3 cannot help: cyclic reuse distance 537MB > 256MB L3). This kernel's
//    partial runs at ~3.8 TB/s -> within a few % of the empirical ceiling.

constexpr int Dh   = 128;
constexpr int Gq   = 4;
constexpr int KVH  = 8;
constexpr int Hq   = 32;
constexpr int Bb   = 32;
constexpr int MB   = 256;
constexpr int PAGE = 16;
constexpr float SCALE = 0.08838834764831845f;

constexpr int NPARTS      = 64;
constexpr int PART_TOKENS = 64;                  // 4 pages per part
constexpr int PG_FLOATS   = PAGE * KVH * Dh;     // 16384 floats = 64 KB
constexpr int ROW_FLOATS  = KVH * Dh;            // 1024 floats per token row

// per-(b,part) workspace floats: acc[32 heads][128] + m[32] + l[32]
constexpr int PART_STRIDE = Hq * Dh + 2 * Hq;    // 4160

struct QuadR { float4 k[4], v[4]; };             // 4 tokens x 4 dims of K and V

__global__ __launch_bounds__(256, 3)
void attn_partial(const float* __restrict__ q,
                  const float* __restrict__ kc,
                  const float* __restrict__ vc,
                  const int*   __restrict__ bt,
                  const int*   __restrict__ cl,
                  float*       __restrict__ ws)
{
    const int part = blockIdx.x & (NPARTS - 1);
    const int b    = blockIdx.x >> 6;

    const int ctx    = cl[b];
    const int pstart = part * PART_TOKENS;
    if (pstart >= ctx) return;
    const int n  = min(PART_TOKENS, ctx - pstart);
    const int TC = (n + 3) >> 2;                 // 4-token chunks, 1..16

    const int t      = threadIdx.x;              // 0..255
    const int kvh    = t >> 5;
    const int lane32 = t & 31;
    const int doff   = lane32 * 4;
    const int t4     = t * 4;

    const int4 pg = *(const int4*)(bt + b * MB + (pstart >> 4));

    float4 qv[Gq];
    {
        const float* qbase = q + (size_t)(b * Hq + kvh * Gq) * Dh + doff;
        #pragma unroll
        for (int g = 0; g < Gq; ++g) {
            float4 x = *(const float4*)(qbase + g * Dh);
            qv[g] = make_float4(x.x * SCALE, x.y * SCALE, x.z * SCALE, x.w * SCALE);
        }
    }

    float4 acc[Gq];
    float  m_run[Gq], l_run[Gq];
    #pragma unroll
    for (int g = 0; g < Gq; ++g) {
        acc[g] = make_float4(0.f, 0.f, 0.f, 0.f);
        m_run[g] = -1e30f;
        l_run[g] = 0.f;
    }

    auto physof = [&](int c) -> int {
        const int p = c >> 2;
        return p == 0 ? pg.x : (p == 1 ? pg.y : (p == 2 ? pg.z : pg.w));
    };

    auto LOADQ = [&](QuadR& H, int c) {
        const size_t off = (size_t)physof(c) * PG_FLOATS
                         + (size_t)((c & 3) * 4) * ROW_FLOATS + t4;
        const float* kp = kc + off;
        const float* vp = vc + off;
        #pragma unroll
        for (int j = 0; j < 4; ++j) {
            H.k[j] = *(const float4*)(kp + j * ROW_FLOATS);
            H.v[j] = *(const float4*)(vp + j * ROW_FLOATS);
        }
    };

    auto COMPUTEQ = [&](const QuadR& H, int c) {
        const int tb = c * 4;
        float s[4][Gq];
        #pragma unroll
        for (int j = 0; j < 4; ++j) {
            const bool vj = (tb + j) < n;
            #pragma unroll
            for (int g = 0; g < Gq; ++g) {
                float d = H.k[j].x * qv[g].x + H.k[j].y * qv[g].y
                        + H.k[j].z * qv[g].z + H.k[j].w * qv[g].w;
                d += __shfl_xor(d, 1);
                d += __shfl_xor(d, 2);
                d += __shfl_xor(d, 4);
                d += __shfl_xor(d, 8);
                d += __shfl_xor(d, 16);          // full dot in all 32 lanes
                s[j][g] = vj ? d : -1e30f;
            }
        }
        #pragma unroll
        for (int g = 0; g < Gq; ++g) {
            const float tm = fmaxf(fmaxf(s[0][g], s[1][g]), fmaxf(s[2][g], s[3][g]));
            const float mn    = fmaxf(m_run[g], tm);
            const float alpha = __expf(m_run[g] - mn);
            m_run[g] = mn;
            const float p0 = __expf(s[0][g] - mn);
            const float p1 = __expf(s[1][g] - mn);
            const float p2 = __expf(s[2][g] - mn);
            const float p3 = __expf(s[3][g] - mn);
            l_run[g] = l_run[g] * alpha + (p0 + p1 + p2 + p3);
            acc[g].x = fmaf(p3, H.v[3].x, fmaf(p2, H.v[2].x,
                       fmaf(p1, H.v[1].x, fmaf(p0, H.v[0].x, acc[g].x * alpha))));
            acc[g].y = fmaf(p3, H.v[3].y, fmaf(p2, H.v[2].y,
                       fmaf(p1, H.v[1].y, fmaf(p0, H.v[0].y, acc[g].y * alpha))));
            acc[g].z = fmaf(p3, H.v[3].z, fmaf(p2, H.v[2].z,
                       fmaf(p1, H.v[1].z, fmaf(p0, H.v[0].z, acc[g].z * alpha))));
            acc[g].w = fmaf(p3, H.v[3].w, fmaf(p2, H.v[2].w,
                       fmaf(p1, H.v[1].w, fmaf(p0, H.v[0].w, acc[g].w * alpha))));
        }
    };

    QuadR A, B;
    LOADQ(A, 0);
    int c = 0;
    while (true) {
        if (c + 1 < TC) LOADQ(B, c + 1);
        COMPUTEQ(A, c);
        ++c; if (c >= TC) break;
        if (c + 1 < TC) LOADQ(A, c + 1);
        COMPUTEQ(B, c);
        ++c; if (c >= TC) break;
    }

    float* wp = ws + (size_t)(b * NPARTS + part) * PART_STRIDE;
    #pragma unroll
    for (int g = 0; g < Gq; ++g)
        *(float4*)(wp + (kvh * Gq + g) * Dh + doff) = acc[g];
    if (lane32 == 0) {
        #pragma unroll
        for (int g = 0; g < Gq; ++g) {
            wp[Hq * Dh + kvh * Gq + g]      = m_run[g];
            wp[Hq * Dh + Hq + kvh * Gq + g] = l_run[g];
        }
    }
}

__global__ __launch_bounds__(256, 4)
void attn_reduce(const float* __restrict__ ws,
                 const int*   __restrict__ cl,
                 float*       __restrict__ out)
{
    const int b       = blockIdx.x >> 2;
    const int quarter = blockIdx.x & 3;
    const int tid     = threadIdx.x;
    const int h       = quarter * 8 + (tid >> 5);
    const int doff    = (tid & 31) * 4;

    const int ctx = cl[b];
    const int np  = min(NPARTS, (ctx + PART_TOKENS - 1) / PART_TOKENS);

    const float* base = ws + (size_t)b * NPARTS * PART_STRIDE;

    float m = -1e30f;
    for (int p = 0; p < np; ++p)
        m = fmaxf(m, base[p * PART_STRIDE + Hq * Dh + h]);

    float L = 0.f;
    float ax = 0.f, ay = 0.f, az = 0.f, aw = 0.f;
    for (int p = 0; p < np; ++p) {
        const float* bp = base + p * PART_STRIDE;
        const float c = __expf(bp[Hq * Dh + h] - m);
        L += bp[Hq * Dh + Hq + h] * c;
        const float4 v = *(const float4*)(bp + h * Dh + doff);
        ax = fmaf(c, v.x, ax);
        ay = fmaf(c, v.y, ay);
        az = fmaf(c, v.z, az);
        aw = fmaf(c, v.w, aw);
    }
    const float inv = 1.f / L;
    float* op = out + (size_t)(b * Hq + h) * Dh + doff;
    *(float4*)op = make_float4(ax * inv, ay * inv, az * inv, aw * inv);
}

extern "C" void kernel_launch(void* const* d_in, const int* in_sizes, int n_in,
                              void* d_out, int out_size, void* d_ws, size_t ws_size,
                              hipStream_t stream) {
    const float* q  = (const float*)d_in[0];
    const float* kc = (const float*)d_in[1];
    const float* vc = (const float*)d_in[2];
    const int*   bt = (const int*)d_in[3];
    const int*   cl = (const int*)d_in[4];
    float* out = (float*)d_out;
    float* ws  = (float*)d_ws;

    attn_partial<<<dim3(Bb * NPARTS), dim3(256), 0, stream>>>(q, kc, vc, bt, cl, ws);
    attn_reduce<<<dim3(Bb * 4), dim3(256), 0, stream>>>(ws, cl, out);
}